// Round 8
// baseline (1616.805 us; speedup 1.0000x reference)
//
#include <hip/hip_runtime.h>
#include <math.h>

#define EMBED 512
#define HEADS 8
#define DH 64
#define MM 256
#define LSEG 17
#define NPAD 4352
#define NTOK 4097
#define N0 4096
#define BATCH 4
#define CIN 1536
#define QSCALE 0.125f
#define BH 32   // BATCH*HEADS
#define NSEG 17 // key segments of 256 for a3v

typedef float fp32x4 __attribute__((ext_vector_type(4)));
typedef short bf16x8 __attribute__((ext_vector_type(8)));
typedef short bf16x4 __attribute__((ext_vector_type(4)));
typedef unsigned short u16;

__device__ __forceinline__ unsigned short f2bf(float f) {
  unsigned int u = __float_as_uint(f);
  u += 0x7fffu + ((u >> 16) & 1u);
  return (unsigned short)(u >> 16);
}
__device__ __forceinline__ float bf2f(unsigned short u) {
  return __uint_as_float((unsigned)u << 16);
}

// ---------------- block reduction helpers (blockDim.x == 256) ----------------
__device__ __forceinline__ float block_sum(float v, float* red) {
  #pragma unroll
  for (int o = 1; o < 64; o <<= 1) v += __shfl_xor(v, o);
  int lane = threadIdx.x & 63, wid = threadIdx.x >> 6;
  if (lane == 0) red[wid] = v;
  __syncthreads();
  float r = red[0] + red[1] + red[2] + red[3];
  __syncthreads();
  return r;
}
__device__ __forceinline__ float block_max(float v, float* red) {
  #pragma unroll
  for (int o = 1; o < 64; o <<= 1) v = fmaxf(v, __shfl_xor(v, o));
  int lane = threadIdx.x & 63, wid = threadIdx.x >> 6;
  if (lane == 0) red[wid] = v;
  __syncthreads();
  float r = fmaxf(fmaxf(red[0], red[1]), fmaxf(red[2], red[3]));
  __syncthreads();
  return r;
}

// fp32 -> bf16 convert (n multiple of 8)
__global__ void f2bf_kernel(const float* __restrict__ in, u16* __restrict__ out, int n) {
  int t = (blockIdx.x * 256 + threadIdx.x) * 8;
  if (t >= n) return;
  float4 a = *(const float4*)&in[t];
  float4 b = *(const float4*)&in[t + 4];
  bf16x8 pk;
  pk[0]=(short)f2bf(a.x); pk[1]=(short)f2bf(a.y); pk[2]=(short)f2bf(a.z); pk[3]=(short)f2bf(a.w);
  pk[4]=(short)f2bf(b.x); pk[5]=(short)f2bf(b.y); pk[6]=(short)f2bf(b.z); pk[7]=(short)f2bf(b.w);
  *(bf16x8*)&out[t] = pk;
}

// ------- bf16-MFMA GEMM  C = A(M,K)bf16 @ W(N,K)bf16^T,  64x128 tile --------
__global__ __launch_bounds__(256) void gemm_abt(
    const u16* __restrict__ A, const u16* __restrict__ W,
    int Mrows, int Ncols, int K, const float* __restrict__ bias,
    float* __restrict__ fout, float* __restrict__ fout2,
    u16* __restrict__ uo0, u16* __restrict__ uo1, u16* __restrict__ uo2,
    int mode)
{
  __shared__ u16 As[64][40];
  __shared__ u16 Ws[128][40];
  int tid = threadIdx.x;
  int lane = tid & 63;
  int wv = tid >> 6;
  int rowBase = blockIdx.y * 64, colBase = blockIdx.x * 128;
  int quad = lane >> 4;
  int l15 = lane & 15;
  int sr = tid >> 2;
  int skc = (tid & 3) * 8;

  fp32x4 acc[8];
  #pragma unroll
  for (int i = 0; i < 8; i++) acc[i] = fp32x4{0,0,0,0};

  for (int kb = 0; kb < K; kb += 32) {
    __syncthreads();
    {
      int grow = rowBase + sr;
      bf16x8 av;
      if (grow < Mrows) av = *(const bf16x8*)&A[(size_t)grow * K + kb + skc];
      else { bf16x8 z = {0,0,0,0,0,0,0,0}; av = z; }
      *(bf16x8*)&As[sr][skc] = av;
    }
    #pragma unroll
    for (int h = 0; h < 2; h++) {
      int r = sr + h * 64;
      *(bf16x8*)&Ws[r][skc] =
          *(const bf16x8*)&W[(size_t)(colBase + r) * K + kb + skc];
    }
    __syncthreads();
    bf16x8 aF = *(const bf16x8*)&As[wv * 16 + l15][quad * 8];
    #pragma unroll
    for (int ct = 0; ct < 8; ct++) {
      bf16x8 bF = *(const bf16x8*)&Ws[ct * 16 + l15][quad * 8];
      acc[ct] = __builtin_amdgcn_mfma_f32_16x16x32_bf16(aF, bF, acc[ct], 0, 0, 0);
    }
  }

  #pragma unroll
  for (int ct = 0; ct < 8; ct++) {
    int col = colBase + ct * 16 + l15;
    #pragma unroll
    for (int i = 0; i < 4; i++) {
      int row = rowBase + wv * 16 + quad * 4 + i;
      if (row >= Mrows) continue;
      float v = acc[ct][i];
      if (mode == 0) {
        v += bias[col];
        v = fmaxf(v, 0.f);
        int b = row / N0, n = row % N0;
        fout[((size_t)b * NTOK + 1 + n) * EMBED + col] = v;
      } else if (mode == 1) {
        int b = row / NPAD, n = row % NPAD;
        int sec = col / EMBED;
        int hh = (col % EMBED) / DH;
        int d = col & 63;
        u16* dst = (sec == 0) ? uo0 : ((sec == 1) ? uo1 : uo2);
        if (sec == 0) v *= QSCALE;
        dst[(((size_t)b * HEADS + hh) * NPAD + n) * DH + d] = f2bf(v);
      } else if (mode == 2) {
        v += bias[col];
        fout[(size_t)row * EMBED + col] += v;
      } else {
        v += bias[col];
        float full = fout[(size_t)row * EMBED + col] + v;
        fout[(size_t)row * EMBED + col] = full;
        int b = row / NTOK, t = row % NTOK;
        if (t > 0) fout2[((size_t)b * N0 + (t - 1)) * EMBED + col] = full;
      }
    }
  }
}

// ---- pinv GEMM (dual-layout bf16): C = gamma*(sgn*(A@B) + beta*A) ----------
__global__ __launch_bounds__(256) void gemm_nn2(
    const u16* __restrict__ A, const u16* __restrict__ Bc,
    u16* __restrict__ Cr, u16* __restrict__ Cc,
    int Nsize, float beta, float sgn, float gamma)
{
  __shared__ u16 As[64][40];
  __shared__ u16 Bs[64][40];
  int batch = blockIdx.z;
  const u16* Ab = A + (size_t)batch * MM * MM;
  const u16* Bb = Bc + (size_t)batch * MM * Nsize;
  int tid = threadIdx.x;
  int lane = tid & 63, wv = tid >> 6, quad = lane >> 4, l15 = lane & 15;
  int rowBase = blockIdx.y * 64, colBase = blockIdx.x * 64;
  int sr = tid >> 2, skc = (tid & 3) * 8;
  fp32x4 acc[4] = {fp32x4{0,0,0,0}, fp32x4{0,0,0,0}, fp32x4{0,0,0,0}, fp32x4{0,0,0,0}};

  for (int kb = 0; kb < MM; kb += 32) {
    __syncthreads();
    *(bf16x8*)&As[sr][skc] = *(const bf16x8*)&Ab[(size_t)(rowBase + sr) * MM + kb + skc];
    *(bf16x8*)&Bs[sr][skc] = *(const bf16x8*)&Bb[(size_t)(colBase + sr) * MM + kb + skc];
    __syncthreads();
    bf16x8 aF = *(const bf16x8*)&As[wv * 16 + l15][quad * 8];
    #pragma unroll
    for (int ct = 0; ct < 4; ct++) {
      bf16x8 bF = *(const bf16x8*)&Bs[ct * 16 + l15][quad * 8];
      acc[ct] = __builtin_amdgcn_mfma_f32_16x16x32_bf16(aF, bF, acc[ct], 0, 0, 0);
    }
  }

  #pragma unroll
  for (int ct = 0; ct < 4; ct++) {
    int col = colBase + ct * 16 + l15;
    #pragma unroll
    for (int i = 0; i < 4; i++) {
      int row = rowBase + wv * 16 + quad * 4 + i;
      float v = sgn * acc[ct][i];
      if (beta != 0.f) v += beta * bf2f(Ab[(size_t)row * MM + col]);
      v *= gamma;
      u16 o = f2bf(v);
      if (Cr) Cr[(size_t)batch * MM * Nsize + (size_t)row * Nsize + col] = o;
      if (Cc) Cc[(size_t)batch * MM * Nsize + (size_t)col * MM + row] = o;
    }
  }
}

// ---------------- small utility kernels ----------------
__global__ void cls_kernel(const float* __restrict__ cls, float* __restrict__ h) {
  int t = blockIdx.x * blockDim.x + threadIdx.x;
  if (t >= BATCH * EMBED) return;
  int b = t / EMBED, c = t % EMBED;
  h[(size_t)b * NTOK * EMBED + c] = cls[c];
}

__global__ void zero_pad_kernel(u16* __restrict__ xpad) {
  int t = blockIdx.x * blockDim.x + threadIdx.x;
  const int per = 255 * EMBED;
  if (t >= BATCH * per) return;
  int b = t / per, r = t % per;
  xpad[(size_t)b * NPAD * EMBED + r] = 0;
}

__global__ __launch_bounds__(256) void ln_pad_kernel(
    const float* __restrict__ h, const float* __restrict__ g,
    const float* __restrict__ be, u16* __restrict__ xpad)
{
  __shared__ float red[4];
  int row = blockIdx.x;
  int b = row / NTOK, j = row % NTOK;
  const float* x = h + (size_t)row * EMBED;
  int tid = threadIdx.x;
  float v0 = x[tid], v1 = x[tid + 256];
  float mu = block_sum(v0 + v1, red) * (1.f / 512.f);
  float d0 = v0 - mu, d1 = v1 - mu;
  float var = block_sum(d0 * d0 + d1 * d1, red) * (1.f / 512.f);
  float inv = 1.f / sqrtf(var + 1e-5f);
  u16* o = xpad + ((size_t)b * NPAD + 255 + j) * EMBED;
  o[tid]       = f2bf(d0 * inv * g[tid]       + be[tid]);
  o[tid + 256] = f2bf(d1 * inv * g[tid + 256] + be[tid + 256]);
}

// landmarks: fp32 qland/kland (for s2/a3v) + bf16 klandB (for attn1 frags)
__global__ __launch_bounds__(256) void landmarks_kernel(
    const u16* __restrict__ q, const u16* __restrict__ k,
    float* __restrict__ qland, float* __restrict__ kland, u16* __restrict__ klandB)
{
  int bh = blockIdx.y;
  int m = blockIdx.x * 4 + (threadIdx.x >> 6);
  int d = threadIdx.x & 63;
  const u16* qb = q + (size_t)bh * NPAD * DH;
  const u16* kb = k + (size_t)bh * NPAD * DH;
  float sq = 0.f, sk = 0.f;
  int base = m * LSEG;
  #pragma unroll
  for (int t = 0; t < LSEG; t++) {
    sq += bf2f(qb[(size_t)(base + t) * DH + d]);
    sk += bf2f(kb[(size_t)(base + t) * DH + d]);
  }
  float kv = sk * (1.f / LSEG);
  qland[((size_t)bh * MM + m) * DH + d] = sq * (1.f / LSEG);
  kland[((size_t)bh * MM + m) * DH + d] = kv;
  klandB[((size_t)bh * MM + m) * DH + d] = f2bf(kv);
}

__global__ __launch_bounds__(256) void s2_softmax_kernel(
    const float* __restrict__ qland, const float* __restrict__ kland,
    u16* __restrict__ a2)
{
  __shared__ float qrow[64];
  __shared__ float red[4];
  int bh = blockIdx.y, m = blockIdx.x, tid = threadIdx.x;
  if (tid < 64) qrow[tid] = qland[((size_t)bh * MM + m) * DH + tid];
  __syncthreads();
  const float* kb = kland + (size_t)bh * MM * DH + (size_t)tid * DH;
  float s = 0.f;
  #pragma unroll 16
  for (int d = 0; d < 64; d++) s += qrow[d] * kb[d];
  float mx = block_max(s, red);
  float e = __expf(s - mx);
  float tot = block_sum(e, red);
  a2[((size_t)bh * MM + m) * MM + tid] = f2bf(e / tot);
}

__global__ void init_denom_kernel(float* __restrict__ denoms) {
  if (threadIdx.x < 2) denoms[threadIdx.x] = 0.f;
}

__global__ __launch_bounds__(256) void denom_kernel(
    const u16* __restrict__ a2, float* __restrict__ denoms)
{
  __shared__ float red[4];
  int bh = blockIdx.x, tid = threadIdx.x;
  const u16* A = a2 + (size_t)bh * MM * MM;
  float rs = 0.f, cs = 0.f;
  for (int j = 0; j < MM; j++) rs += bf2f(A[(size_t)tid * MM + j]);
  for (int i = 0; i < MM; i++) cs += bf2f(A[(size_t)i * MM + tid]);
  float mr = block_max(rs, red);
  float mc = block_max(cs, red);
  if (tid == 0) {
    atomicMax((int*)&denoms[0], __float_as_int(mr));
    atomicMax((int*)&denoms[1], __float_as_int(mc));
  }
}

// z0: zr = a2^T/denom (row-major), zc = a2/denom (= z^T row-major)
__global__ __launch_bounds__(256) void z0_trans_kernel(
    const u16* __restrict__ a2, const float* __restrict__ denoms,
    u16* __restrict__ zr, u16* __restrict__ zc)
{
  __shared__ u16 tile[64][72];
  int bh = blockIdx.z, i0 = blockIdx.y * 64, j0 = blockIdx.x * 64;
  int tid = threadIdx.x;
  float inv = 1.f / (denoms[0] * denoms[1]);
  const u16* Ab = a2 + (size_t)bh * MM * MM;
  #pragma unroll
  for (int it = 0; it < 4; it++) {
    int idx = it * 1024 + tid * 4;
    int r = idx >> 6, c = idx & 63;
    bf16x4 v = *(const bf16x4*)&Ab[(size_t)(i0 + r) * MM + j0 + c];
    u16 o[4];
    #pragma unroll
    for (int j = 0; j < 4; j++) o[j] = f2bf(bf2f((unsigned short)v[j]) * inv);
    *(bf16x4*)&zc[(size_t)bh * MM * MM + (size_t)(i0 + r) * MM + j0 + c] = *(bf16x4*)o;
    #pragma unroll
    for (int j = 0; j < 4; j++) tile[c + j][r] = o[j];
  }
  __syncthreads();
  #pragma unroll
  for (int it = 0; it < 4; it++) {
    int idx = it * 1024 + tid * 4;
    int r = idx >> 6, c = idx & 63;
    u16 o[4] = {tile[r][c], tile[r][c + 1], tile[r][c + 2], tile[r][c + 3]};
    *(bf16x4*)&zr[(size_t)bh * MM * MM + (size_t)(j0 + r) * MM + i0 + c] = *(bf16x4*)o;
  }
}

// ---- MFMA a3@v partial flash: block = 64 landmarks x 256-key segment --------
__global__ __launch_bounds__(256) void a3v_part_mfma(
    const float* __restrict__ qland, const u16* __restrict__ k,
    const u16* __restrict__ v, u16* __restrict__ Opart,
    float* __restrict__ mpart, float* __restrict__ lpart)
{
  __shared__ __align__(16) u16 qs[64][40];
  __shared__ __align__(16) u16 ks[256][72];   // reused for P[64][264]
  __shared__ __align__(16) u16 vt[64][72];
  int tid = threadIdx.x;
  int lane = tid & 63, wv = tid >> 6, quad = lane >> 4, l15 = lane & 15;
  int bh = blockIdx.y;
  int ltile = blockIdx.x & 3;
  int seg = blockIdx.x >> 2;
  int l0 = ltile * 64;
  int key0 = seg * 256;
  const float* qb = qland + (size_t)bh * MM * DH;
  const u16* kb = k + (size_t)bh * NPAD * DH;
  const u16* vb = v + (size_t)bh * NPAD * DH;

  {
    int sr = tid >> 2, dc = (tid & 3) * 16;
    const float4* p = (const float4*)&qb[(size_t)(l0 + sr) * DH + dc];
    float4 v0 = p[0], v1 = p[1], v2 = p[2], v3 = p[3];
    float va[16] = {v0.x,v0.y,v0.z,v0.w, v1.x,v1.y,v1.z,v1.w,
                    v2.x,v2.y,v2.z,v2.w, v3.x,v3.y,v3.z,v3.w};
    bf16x8 p0, p1;
    #pragma unroll
    for (int j = 0; j < 8; j++) { p0[j] = (short)f2bf(va[j]); p1[j] = (short)f2bf(va[8 + j]); }
    *(bf16x8*)&qs[sr][dc] = p0;
    *(bf16x8*)&qs[sr][dc + 8] = p1;
  }
  #pragma unroll
  for (int i = 0; i < 16; i++) {
    int idx = i * 1024 + tid * 4;
    int r = idx >> 6, c = idx & 63;
    *(bf16x4*)&ks[r][c] = *(const bf16x4*)&kb[(size_t)(key0 + r) * DH + c];
  }
  __syncthreads();

  fp32x4 sacc[16];
  #pragma unroll
  for (int ct = 0; ct < 16; ct++) sacc[ct] = fp32x4{0,0,0,0};
  bf16x8 aF0 = *(const bf16x8*)&qs[wv * 16 + l15][quad * 8];
  bf16x8 aF1 = *(const bf16x8*)&qs[wv * 16 + l15][32 + quad * 8];
  #pragma unroll
  for (int ct = 0; ct < 16; ct++) {
    bf16x8 b0 = *(const bf16x8*)&ks[ct * 16 + l15][quad * 8];
    bf16x8 b1 = *(const bf16x8*)&ks[ct * 16 + l15][32 + quad * 8];
    sacc[ct] = __builtin_amdgcn_mfma_f32_16x16x32_bf16(aF0, b0, sacc[ct], 0, 0, 0);
    sacc[ct] = __builtin_amdgcn_mfma_f32_16x16x32_bf16(aF1, b1, sacc[ct], 0, 0, 0);
  }

  float mrow[4], lrow[4];
  #pragma unroll
  for (int i = 0; i < 4; i++) {
    float m = -3.0e38f;
    #pragma unroll
    for (int ct = 0; ct < 16; ct++) m = fmaxf(m, sacc[ct][i]);
    #pragma unroll
    for (int o = 1; o < 16; o <<= 1) m = fmaxf(m, __shfl_xor(m, o));
    float s = 0.f;
    #pragma unroll
    for (int ct = 0; ct < 16; ct++) {
      float e = __expf(sacc[ct][i] - m);
      sacc[ct][i] = e;
      s += e;
    }
    #pragma unroll
    for (int o = 1; o < 16; o <<= 1) s += __shfl_xor(s, o);
    mrow[i] = m;
    lrow[i] = s;
  }
  __syncthreads();
  u16* P = &ks[0][0];
  #pragma unroll
  for (int ct = 0; ct < 16; ct++)
    #pragma unroll
    for (int i = 0; i < 4; i++)
      P[(size_t)(wv * 16 + quad * 4 + i) * 264 + ct * 16 + l15] = f2bf(sacc[ct][i]);
  __syncthreads();

  fp32x4 oacc[4] = {fp32x4{0,0,0,0}, fp32x4{0,0,0,0}, fp32x4{0,0,0,0}, fp32x4{0,0,0,0}};
  int dh = tid & 63, kgrp = tid >> 6;
  for (int ch = 0; ch < 4; ch++) {
    if (ch) __syncthreads();
    {
      int kbase = kgrp * 16;
      #pragma unroll
      for (int g = 0; g < 4; g++) {
        u16 pk[4];
        #pragma unroll
        for (int r = 0; r < 4; r++)
          pk[r] = vb[(size_t)(key0 + ch * 64 + kbase + g * 4 + r) * DH + dh];
        *(bf16x4*)&vt[dh][kbase + g * 4] = *(bf16x4*)pk;
      }
    }
    __syncthreads();
    #pragma unroll
    for (int ks2 = 0; ks2 < 2; ks2++) {
      bf16x8 aP = *(const bf16x8*)&P[(size_t)(wv * 16 + l15) * 264 + ch * 64 + ks2 * 32 + quad * 8];
      #pragma unroll
      for (int ct = 0; ct < 4; ct++) {
        bf16x8 bV = *(const bf16x8*)&vt[ct * 16 + l15][ks2 * 32 + quad * 8];
        oacc[ct] = __builtin_amdgcn_mfma_f32_16x16x32_bf16(aP, bV, oacc[ct], 0, 0, 0);
      }
    }
  }

  size_t base = ((size_t)seg * BH + bh) * MM + l0;
  #pragma unroll
  for (int ct = 0; ct < 4; ct++)
    #pragma unroll
    for (int i = 0; i < 4; i++) {
      int row = wv * 16 + quad * 4 + i;
      Opart[(base + row) * DH + ct * 16 + l15] = f2bf(oacc[ct][i]);
    }
  if (l15 == 0) {
    #pragma unroll
    for (int i = 0; i < 4; i++) {
      int row = wv * 16 + quad * 4 + i;
      mpart[base + row] = mrow[i];
      lpart[base + row] = lrow[i];
    }
  }
}

// merge partials -> kv^T (col-major for the z@kv GEMM's B operand)
__global__ __launch_bounds__(256) void a3v_merge_kernel(
    const u16* __restrict__ Opart, const float* __restrict__ mpart,
    const float* __restrict__ lpart, u16* __restrict__ kvT)
{
  int bh = blockIdx.y;
  int lbase = blockIdx.x * 64;
  int d = threadIdx.x & 63, lsub = threadIdx.x >> 6;
  for (int li = lsub; li < 64; li += 4) {
    int lm = lbase + li;
    float M = -3.0e38f;
    #pragma unroll
    for (int s = 0; s < NSEG; s++)
      M = fmaxf(M, mpart[((size_t)s * BH + bh) * MM + lm]);
    float L = 0.f, O = 0.f;
    #pragma unroll
    for (int s = 0; s < NSEG; s++) {
      size_t idx = ((size_t)s * BH + bh) * MM + lm;
      float w = __expf(mpart[idx] - M);
      L += lpart[idx] * w;
      O += bf2f(Opart[idx * DH + d]) * w;
    }
    kvT[((size_t)bh * DH + d) * MM + lm] = f2bf(O / L);
  }
}

// Toeplitz conv weights: toepB[layer][head][r=0..63][t=0..95] = w[t-r] (banded)
__global__ void prep_toep_kernel(const float* __restrict__ resw0,
                                 const float* __restrict__ resw1,
                                 u16* __restrict__ toepB)
{
  int i = blockIdx.x * 256 + threadIdx.x;
  if (i >= 2 * 8 * 64 * 96) return;
  int t = i % 96, r = (i / 96) % 64, hh = (i / (96 * 64)) % 8, l = i / (96 * 64 * 8);
  const float* rw = l ? resw1 : resw0;
  int tap = t - r;
  float v = (tap >= 0 && tap <= 32) ? rw[hh * 33 + tap] : 0.f;
  toepB[i] = f2bf(v);
}

// ---- attn1: global-sourced MFMA frags + Toeplitz-MFMA conv, 64 rows/block ---
// LDS: single 33.8 KB buffer (P, then reused as vwinT[64][104])
__global__ __launch_bounds__(256, 4) void attn1_mfma(
    const u16* __restrict__ q, const u16* __restrict__ klandB,
    const u16* __restrict__ kv2T, const u16* __restrict__ v,
    const u16* __restrict__ toep, u16* __restrict__ attn)
{
  __shared__ __align__(16) u16 buf[64 * 264];
  int tid = threadIdx.x;
  int lane = tid & 63, wv = tid >> 6, quad = lane >> 4, l15 = lane & 15;
  int bh = blockIdx.y, b = bh >> 3, hh = bh & 7;
  int n0 = 255 + blockIdx.x * 64;
  const u16* qb  = q + (size_t)bh * NPAD * DH;
  const u16* klb = klandB + (size_t)bh * MM * DH;
  const u16* kvb = kv2T + (size_t)bh * DH * MM;
  const u16* vb  = v + (size_t)bh * NPAD * DH;
  const u16* tb  = toep + (size_t)hh * 64 * 96;

  // S = Q @ kland^T (all fragments from global)
  int qrow = n0 + wv * 16 + l15; if (qrow > NPAD - 1) qrow = NPAD - 1;
  bf16x8 aF0 = *(const bf16x8*)&qb[(size_t)qrow * DH + quad * 8];
  bf16x8 aF1 = *(const bf16x8*)&qb[(size_t)qrow * DH + 32 + quad * 8];
  fp32x4 sacc[16];
  #pragma unroll
  for (int ct = 0; ct < 16; ct++) sacc[ct] = fp32x4{0,0,0,0};
  #pragma unroll
  for (int ct = 0; ct < 16; ct++) {
    bf16x8 b0 = *(const bf16x8*)&klb[(size_t)(ct * 16 + l15) * DH + quad * 8];
    bf16x8 b1 = *(const bf16x8*)&klb[(size_t)(ct * 16 + l15) * DH + 32 + quad * 8];
    sacc[ct] = __builtin_amdgcn_mfma_f32_16x16x32_bf16(aF0, b0, sacc[ct], 0, 0, 0);
    sacc[ct] = __builtin_amdgcn_mfma_f32_16x16x32_bf16(aF1, b1, sacc[ct], 0, 0, 0);
  }
  // register softmax (row = quad*4+i, cols over ct x l15)
  #pragma unroll
  for (int i = 0; i < 4; i++) {
    float m = -3.0e38f;
    #pragma unroll
    for (int ct = 0; ct < 16; ct++) m = fmaxf(m, sacc[ct][i]);
    #pragma unroll
    for (int o = 1; o < 16; o <<= 1) m = fmaxf(m, __shfl_xor(m, o));
    float s = 0.f;
    #pragma unroll
    for (int ct = 0; ct < 16; ct++) {
      float e = __expf(sacc[ct][i] - m);
      sacc[ct][i] = e;
      s += e;
    }
    #pragma unroll
    for (int o = 1; o < 16; o <<= 1) s += __shfl_xor(s, o);
    float inv = 1.f / s;
    #pragma unroll
    for (int ct = 0; ct < 16; ct++) sacc[ct][i] *= inv;
  }
  // write P (normalized bf16), stride 264
  #pragma unroll
  for (int ct = 0; ct < 16; ct++)
    #pragma unroll
    for (int i = 0; i < 4; i++)
      buf[(size_t)(wv * 16 + quad * 4 + i) * 264 + ct * 16 + l15] = f2bf(sacc[ct][i]);
  __syncthreads();

  // O = P @ kv2 (aP from LDS, bV from global kv2T)
  fp32x4 oacc[4] = {fp32x4{0,0,0,0}, fp32x4{0,0,0,0}, fp32x4{0,0,0,0}, fp32x4{0,0,0,0}};
  #pragma unroll
  for (int ks = 0; ks < 8; ks++) {
    bf16x8 aP = *(const bf16x8*)&buf[(size_t)(wv * 16 + l15) * 264 + ks * 32 + quad * 8];
    #pragma unroll
    for (int ct = 0; ct < 4; ct++) {
      bf16x8 bV = *(const bf16x8*)&kvb[(size_t)(ct * 16 + l15) * MM + ks * 32 + quad * 8];
      oacc[ct] = __builtin_amdgcn_mfma_f32_16x16x32_bf16(aP, bV, oacc[ct], 0, 0, 0);
    }
  }
  __syncthreads();   // P dead; reuse buf as vwinT[64][104]

  // stage v window transposed: vwinT[d][t], t = n - (n0-16), coalesced reads
  {
    int d = lane;
    #pragma unroll
    for (int tt4 = 0; tt4 < 6; tt4++) {
      u16 vals[4];
      #pragma unroll
      for (int j = 0; j < 4; j++) {
        int t = wv * 24 + tt4 * 4 + j;
        int g = n0 - 16 + t;
        vals[j] = (g <= NPAD - 1) ? vb[(size_t)g * DH + d] : (u16)0;
      }
      *(bf16x4*)&buf[d * 104 + wv * 24 + tt4 * 4] = *(bf16x4*)vals;
    }
  }
  __syncthreads();

  // conv: oacc += Toep(64x96) @ vwinT^T  (aT from global, bW from LDS)
  #pragma unroll
  for (int kc = 0; kc < 3; kc++) {
    bf16x8 aT = *(const bf16x8*)&tb[(size_t)(wv * 16 + l15) * 96 + kc * 32 + quad * 8];
    #pragma unroll
    for (int ct = 0; ct < 4; ct++) {
      bf16x8 bW = *(const bf16x8*)&buf[(ct * 16 + l15) * 104 + kc * 32 + quad * 8];
      oacc[ct] = __builtin_amdgcn_mfma_f32_16x16x32_bf16(aT, bW, oacc[ct], 0, 0, 0);
    }
  }

  #pragma unroll
  for (int ct = 0; ct < 4; ct++) {
    int c = ct * 16 + l15;
    #pragma unroll
    for (int i = 0; i < 4; i++) {
      int rl = wv * 16 + quad * 4 + i;
      int n = n0 + rl;
      if (n > NPAD - 1) continue;
      attn[((size_t)b * NTOK + (n - 255)) * EMBED + hh * DH + c] = f2bf(oacc[ct][i]);
    }
  }
}

// combine 7x7 + 5x5 + 3x3 + identity into one 7x7 depthwise kernel
__global__ void prep_wcomb_kernel(
    const float* __restrict__ pw7, const float* __restrict__ pw5,
    const float* __restrict__ pw3, const float* __restrict__ pb7,
    const float* __restrict__ pb5, const float* __restrict__ pb3,
    float* __restrict__ wcomb, float* __restrict__ biasc)
{
  int i = blockIdx.x * blockDim.x + threadIdx.x;
  if (i < EMBED * 49) {
    int c = i / 49, tap = i % 49;
    int ky = tap / 7, kx = tap % 7;
    float v = pw7[c * 49 + tap];
    if (ky >= 1 && ky <= 5 && kx >= 1 && kx <= 5) v += pw5[c * 25 + (ky - 1) * 5 + (kx - 1)];
    if (ky >= 2 && ky <= 4 && kx >= 2 && kx <= 4) v += pw3[c * 9 + (ky - 2) * 3 + (kx - 2)];
    if (ky == 3 && kx == 3) v += 1.f;
    wcomb[tap * EMBED + c] = v;
  }
  if (i < EMBED) biasc[i] = pb7[i] + pb5[i] + pb3[i];
}

// float4-per-thread depthwise conv: block (32,8) = 128 ch x 8 positions
__global__ __launch_bounds__(256) void dwconv_kernel(
    const float* __restrict__ tmp, const float* __restrict__ wcomb,
    const float* __restrict__ biasc, float* __restrict__ h)
{
  __shared__ float4 wsm[49][32];
  int tx = threadIdx.x;
  int ty = threadIdx.y;
  int cb = blockIdx.x * 128;
  int c = cb + tx * 4;
  int b = blockIdx.z;
  int n = blockIdx.y * 8 + ty;
  int y = n >> 6, x = n & 63;
  int tid = ty * 32 + tx;
  for (int i = tid; i < 49 * 32; i += 256) {
    int tap = i >> 5, g = i & 31;
    wsm[tap][g] = *(const float4*)&wcomb[tap * EMBED + cb + g * 4];
  }
  __syncthreads();
  const float* src = tmp + (size_t)b * N0 * EMBED;
  float4 acc = *(const float4*)&biasc[c];
  #pragma unroll
  for (int ky = 0; ky < 7; ky++) {
    int yy = y + ky - 3;
    if (yy < 0 || yy >= 64) continue;
    #pragma unroll
    for (int kx = 0; kx < 7; kx++) {
      int xx = x + kx - 3;
      if (xx < 0 || xx >= 64) continue;
      float4 vv = *(const float4*)&src[((size_t)yy * 64 + xx) * EMBED + c];
      float4 w = wsm[ky * 7 + kx][tx];
      acc.x += vv.x * w.x;
      acc.y += vv.y * w.y;
      acc.z += vv.z * w.z;
      acc.w += vv.w * w.w;
    }
  }
  *(float4*)&h[((size_t)b * NTOK + 1 + n) * EMBED + c] = acc;
}

__global__ __launch_bounds__(256) void final_kernel(
    const float* __restrict__ h, const float* __restrict__ g,
    const float* __restrict__ be, const float* __restrict__ W2,
    const float* __restrict__ b2, float* __restrict__ out)
{
  __shared__ float red[4];
  int b = blockIdx.x, tid = threadIdx.x;
  const float* x = h + (size_t)b * NTOK * EMBED;
  float v0 = x[tid], v1 = x[tid + 256];
  float mu = block_sum(v0 + v1, red) * (1.f / 512.f);
  float d0 = v0 - mu, d1 = v1 - mu;
  float var = block_sum(d0 * d0 + d1 * d1, red) * (1.f / 512.f);
  float inv = 1.f / sqrtf(var + 1e-5f);
  float xn0 = d0 * inv * g[tid] + be[tid];
  float xn1 = d1 * inv * g[tid + 256] + be[tid + 256];
  float l0 = block_sum(xn0 * W2[tid] + xn1 * W2[tid + 256], red);
  float l1 = block_sum(xn0 * W2[512 + tid] + xn1 * W2[512 + tid + 256], red);
  if (tid == 0) {
    l0 += b2[0]; l1 += b2[1];
    out[b * 2 + 0] = l0;
    out[b * 2 + 1] = l1;
    float mx = fmaxf(l0, l1);
    float e0 = expf(l0 - mx), e1 = expf(l1 - mx);
    float s = e0 + e1;
    out[8 + b * 2 + 0] = e0 / s;
    out[8 + b * 2 + 1] = e1 / s;
    out[16 + b] = (l1 > l0) ? 1.f : 0.f;
  }
}

// ------------------------------- host side -----------------------------------
extern "C" void kernel_launch(void* const* d_in, const int* in_sizes, int n_in,
                              void* d_out, int out_size, void* d_ws, size_t ws_size,
                              hipStream_t stream)
{
  const float* data = (const float*)d_in[0];
  const float* W1   = (const float*)d_in[1];
  const float* b1   = (const float*)d_in[2];
  const float* cls  = (const float*)d_in[3];
  const float* lng[2]  = {(const float*)d_in[4],  (const float*)d_in[10]};
  const float* lnb[2]  = {(const float*)d_in[5],  (const float*)d_in[11]};
  const float* Wqkv[2] = {(const float*)d_in[6],  (const float*)d_in[12]};
  const float* Wo[2]   = {(const float*)d_in[7],  (const float*)d_in[13]};
  const float* bo[2]   = {(const float*)d_in[8],  (const float*)d_in[14]};
  const float* resw[2] = {(const float*)d_in[9],  (const float*)d_in[15]};
  const float* pw7 = (const float*)d_in[16];
  const float* pb7 = (const float*)d_in[17];
  const float* pw5 = (const float*)d_in[18];
  const float* pb5 = (const float*)d_in[19];
  const float* pw3 = (const float*)d_in[20];
  const float* pb3 = (const float*)d_in[21];
  const float* lnfg = (const float*)d_in[22];
  const float* lnfb = (const float*)d_in[23];
  const float* W2  = (const float*)d_in[24];
  const float* b2  = (const float*)d_in[25];

  float* ws = (float*)d_ws;
  size_t off = 0;
  auto alloc = [&](size_t n) { float* p = ws + off; off += n; return p; };
  float* hbuf   = alloc((size_t)BATCH * NTOK * EMBED);          // fp32
  float* xpadf  = alloc((size_t)BATCH * NPAD * EMBED);          // bf16 (half) + attn reuse
  float* qbuff  = alloc((size_t)BH * NPAD * DH);                // q bf16 / databf / conv tmp fp32
  float* kbuff  = alloc((size_t)BH * NPAD * DH);                // k bf16 (half)
  float* vbuff  = alloc((size_t)BH * NPAD * DH);                // v bf16 (half) + W1bf tail
  float* qland  = alloc((size_t)BH * MM * DH);
  float* kland  = alloc((size_t)BH * MM * DH);
  float* klandBf= alloc((size_t)BH * MM * DH / 2);              // bf16
  float* a2f    = alloc((size_t)BH * MM * MM / 2);              // bf16
  float* zaRf   = alloc((size_t)BH * MM * MM / 2);
  float* zaCf   = alloc((size_t)BH * MM * MM / 2);
  float* zbRf   = alloc((size_t)BH * MM * MM / 2);
  float* zbCf   = alloc((size_t)BH * MM * MM / 2);
  float* xzRf   = alloc((size_t)BH * MM * MM / 2);
  float* xzCf   = alloc((size_t)BH * MM * MM / 2);
  float* t1Cf   = alloc((size_t)BH * MM * MM / 2);
  float* t2Cf   = alloc((size_t)BH * MM * MM / 2);
  float* kvTf   = alloc((size_t)BH * MM * DH / 2);
  float* kv2Tf  = alloc((size_t)BH * MM * DH / 2);
  float* wqkvbf = alloc((size_t)2 * 3 * EMBED * EMBED / 2);     // bf16 x2 layers
  float* wobf   = alloc((size_t)2 * EMBED * EMBED / 2);
  float* toepf  = alloc((size_t)2 * 8 * 64 * 96 / 2);           // bf16 toeplitz x2 layers
  float* wcomb  = alloc(49 * EMBED);
  float* biasc  = alloc(EMBED);
  float* denoms = alloc(64);
  float* mpart  = alloc((size_t)NSEG * BH * MM);
  float* lpart  = alloc((size_t)NSEG * BH * MM);

  u16* xpadB = (u16*)xpadf;
  u16* qB = (u16*)qbuff;
  u16* kB = (u16*)kbuff;
  u16* vB = (u16*)vbuff;
  u16* klandB = (u16*)klandBf;
  u16* a2B = (u16*)a2f;
  u16* zaR = (u16*)zaRf; u16* zaC = (u16*)zaCf;
  u16* zbR = (u16*)zbRf; u16* zbC = (u16*)zbCf;
  u16* xzR = (u16*)xzRf; u16* xzC = (u16*)xzCf;
  u16* t1C = (u16*)t1Cf; u16* t2C = (u16*)t2Cf;
  u16* kvT = (u16*)kvTf; u16* kv2T = (u16*)kv2Tf;
  u16* attnB = xpadB;
  u16* OpartB = zaR;                       // overlay: free until z0_trans
  u16* databf = (u16*)qbuff;               // overlay: consumed by input GEMM only
  u16* W1bf = (u16*)vbuff;                 // overlay: consumed by input GEMM only
  u16* WqkvB[2] = {(u16*)wqkvbf, (u16*)wqkvbf + (size_t)3 * EMBED * EMBED};
  u16* WoB[2]   = {(u16*)wobf,   (u16*)wobf + (size_t)EMBED * EMBED};
  u16* toepB[2] = {(u16*)toepf,  (u16*)toepf + (size_t)8 * 64 * 96};
  float* convtmp = qbuff;

  // ---- one-time bf16 conversions / prep ----
  int ndata = BATCH * N0 * CIN;
  f2bf_kernel<<<dim3((ndata / 8 + 255) / 256), 256, 0, stream>>>(data, databf, ndata);
  f2bf_kernel<<<dim3((EMBED * CIN / 8 + 255) / 256), 256, 0, stream>>>(W1, W1bf, EMBED * CIN);
  for (int l = 0; l < 2; l++) {
    f2bf_kernel<<<dim3((3 * EMBED * EMBED / 8 + 255) / 256), 256, 0, stream>>>(Wqkv[l], WqkvB[l], 3 * EMBED * EMBED);
    f2bf_kernel<<<dim3((EMBED * EMBED / 8 + 255) / 256), 256, 0, stream>>>(Wo[l], WoB[l], EMBED * EMBED);
  }
  prep_toep_kernel<<<dim3((2 * 8 * 64 * 96 + 255) / 256), 256, 0, stream>>>(
      resw[0], resw[1], (u16*)toepf);

  gemm_abt<<<dim3(EMBED / 128, (BATCH * N0) / 64), 256, 0, stream>>>(
      databf, W1bf, BATCH * N0, EMBED, CIN, b1, hbuf, nullptr, nullptr, nullptr, nullptr, 0);
  cls_kernel<<<dim3((BATCH * EMBED + 255) / 256), 256, 0, stream>>>(cls, hbuf);

  for (int layer = 0; layer < 2; layer++) {
    ln_pad_kernel<<<dim3(BATCH * NTOK), 256, 0, stream>>>(hbuf, lng[layer], lnb[layer], xpadB);
    zero_pad_kernel<<<dim3((BATCH * 255 * EMBED + 255) / 256), 256, 0, stream>>>(xpadB);
    gemm_abt<<<dim3((3 * EMBED) / 128, (BATCH * NPAD) / 64), 256, 0, stream>>>(
        xpadB, WqkvB[layer], BATCH * NPAD, 3 * EMBED, EMBED, nullptr,
        nullptr, nullptr, qB, kB, vB, 1);
    landmarks_kernel<<<dim3(MM / 4, BH), 256, 0, stream>>>(qB, kB, qland, kland, klandB);
    s2_softmax_kernel<<<dim3(MM, BH), 256, 0, stream>>>(qland, kland, a2B);
    init_denom_kernel<<<1, 64, 0, stream>>>(denoms);
    denom_kernel<<<dim3(BH), 256, 0, stream>>>(a2B, denoms);

    // a3@v before pinv so Opart can overlay the pinv scratch
    a3v_part_mfma<<<dim3(4 * NSEG, BH), 256, 0, stream>>>(
        qland, kB, vB, OpartB, mpart, lpart);
    a3v_merge_kernel<<<dim3(MM / 64, BH), 256, 0, stream>>>(OpartB, mpart, lpart, kvT);

    z0_trans_kernel<<<dim3(4, 4, BH), 256, 0, stream>>>(a2B, denoms, zaR, zaC);
    u16 *zinR = zaR, *zinC = zaC, *zoutR = zbR, *zoutC = zbC;
    for (int it = 0; it < 6; it++) {
      gemm_nn2<<<dim3(4, 4, BH), 256, 0, stream>>>(a2B, zinC, xzR, xzC, MM, 0.f, 1.f, 1.f);
      gemm_nn2<<<dim3(4, 4, BH), 256, 0, stream>>>(xzR, xzC, nullptr, t1C, MM, 7.f, -1.f, 1.f);
      gemm_nn2<<<dim3(4, 4, BH), 256, 0, stream>>>(xzR, t1C, nullptr, t2C, MM, 15.f, -1.f, 1.f);
      gemm_nn2<<<dim3(4, 4, BH), 256, 0, stream>>>(zinR, t2C, zoutR, zoutC, MM, 13.f, -1.f, 0.25f);
      u16* t;
      t = zinR; zinR = zoutR; zoutR = t;
      t = zinC; zinC = zoutC; zoutC = t;
    }
    // kv2T[dh][m] = (z @ kv)^T
    gemm_nn2<<<dim3(1, 4, BH), 256, 0, stream>>>(zinR, kvT, nullptr, kv2T, DH, 0.f, 1.f, 1.f);
    attn1_mfma<<<dim3((NTOK + 63) / 64, BH), 256, 0, stream>>>(
        qB, klandB, kv2T, vB, toepB[layer], attnB);
    gemm_abt<<<dim3(EMBED / 128, (BATCH * NTOK + 63) / 64), 256, 0, stream>>>(
        attnB, WoB[layer], BATCH * NTOK, EMBED, EMBED, bo[layer], hbuf,
        (layer == 0) ? convtmp : nullptr, nullptr, nullptr, nullptr,
        (layer == 0) ? 3 : 2);

    if (layer == 0) {
      prep_wcomb_kernel<<<dim3((EMBED * 49 + 255) / 256), 256, 0, stream>>>(
          pw7, pw5, pw3, pb7, pb5, pb3, wcomb, biasc);
      dwconv_kernel<<<dim3(EMBED / 128, N0 / 8, BATCH), dim3(32, 8), 0, stream>>>(
          convtmp, wcomb, biasc, hbuf);
    }
  }

  final_kernel<<<dim3(BATCH), 256, 0, stream>>>(hbuf, lnfg, lnfb, W2, b2, (float*)d_out);
}

// Round 9
// 1589.190 us; speedup vs baseline: 1.0174x; 1.0174x over previous
//
#include <hip/hip_runtime.h>
#include <math.h>

#define EMBED 512
#define HEADS 8
#define DH 64
#define MM 256
#define LSEG 17
#define NPAD 4352
#define NTOK 4097
#define N0 4096
#define BATCH 4
#define CIN 1536
#define QSCALE 0.125f
#define BH 32   // BATCH*HEADS
#define NSEG 17 // key segments of 256 for a3v

typedef float fp32x4 __attribute__((ext_vector_type(4)));
typedef short bf16x8 __attribute__((ext_vector_type(8)));
typedef short bf16x4 __attribute__((ext_vector_type(4)));
typedef unsigned short u16;

__device__ __forceinline__ unsigned short f2bf(float f) {
  unsigned int u = __float_as_uint(f);
  u += 0x7fffu + ((u >> 16) & 1u);
  return (unsigned short)(u >> 16);
}
__device__ __forceinline__ float bf2f(unsigned short u) {
  return __uint_as_float((unsigned)u << 16);
}

// ---------------- block reduction helpers (blockDim.x == 256) ----------------
__device__ __forceinline__ float block_sum(float v, float* red) {
  #pragma unroll
  for (int o = 1; o < 64; o <<= 1) v += __shfl_xor(v, o);
  int lane = threadIdx.x & 63, wid = threadIdx.x >> 6;
  if (lane == 0) red[wid] = v;
  __syncthreads();
  float r = red[0] + red[1] + red[2] + red[3];
  __syncthreads();
  return r;
}
__device__ __forceinline__ float block_max(float v, float* red) {
  #pragma unroll
  for (int o = 1; o < 64; o <<= 1) v = fmaxf(v, __shfl_xor(v, o));
  int lane = threadIdx.x & 63, wid = threadIdx.x >> 6;
  if (lane == 0) red[wid] = v;
  __syncthreads();
  float r = fmaxf(fmaxf(red[0], red[1]), fmaxf(red[2], red[3]));
  __syncthreads();
  return r;
}

// fp32 -> bf16 convert (n multiple of 8)
__global__ void f2bf_kernel(const float* __restrict__ in, u16* __restrict__ out, int n) {
  int t = (blockIdx.x * 256 + threadIdx.x) * 8;
  if (t >= n) return;
  float4 a = *(const float4*)&in[t];
  float4 b = *(const float4*)&in[t + 4];
  bf16x8 pk;
  pk[0]=(short)f2bf(a.x); pk[1]=(short)f2bf(a.y); pk[2]=(short)f2bf(a.z); pk[3]=(short)f2bf(a.w);
  pk[4]=(short)f2bf(b.x); pk[5]=(short)f2bf(b.y); pk[6]=(short)f2bf(b.z); pk[7]=(short)f2bf(b.w);
  *(bf16x8*)&out[t] = pk;
}

// ------- bf16-MFMA GEMM  C = A(M,K)bf16 @ W(N,K)bf16^T,  64x128 tile --------
__global__ __launch_bounds__(256) void gemm_abt(
    const u16* __restrict__ A, const u16* __restrict__ W,
    int Mrows, int Ncols, int K, const float* __restrict__ bias,
    float* __restrict__ fout, float* __restrict__ fout2,
    u16* __restrict__ uo0, u16* __restrict__ uo1, u16* __restrict__ uo2,
    int mode)
{
  __shared__ u16 As[64][40];
  __shared__ u16 Ws[128][40];
  int tid = threadIdx.x;
  int lane = tid & 63;
  int wv = tid >> 6;
  int rowBase = blockIdx.y * 64, colBase = blockIdx.x * 128;
  int quad = lane >> 4;
  int l15 = lane & 15;
  int sr = tid >> 2;
  int skc = (tid & 3) * 8;

  fp32x4 acc[8];
  #pragma unroll
  for (int i = 0; i < 8; i++) acc[i] = fp32x4{0,0,0,0};

  for (int kb = 0; kb < K; kb += 32) {
    __syncthreads();
    {
      int grow = rowBase + sr;
      bf16x8 av;
      if (grow < Mrows) av = *(const bf16x8*)&A[(size_t)grow * K + kb + skc];
      else { bf16x8 z = {0,0,0,0,0,0,0,0}; av = z; }
      *(bf16x8*)&As[sr][skc] = av;
    }
    #pragma unroll
    for (int h = 0; h < 2; h++) {
      int r = sr + h * 64;
      *(bf16x8*)&Ws[r][skc] =
          *(const bf16x8*)&W[(size_t)(colBase + r) * K + kb + skc];
    }
    __syncthreads();
    bf16x8 aF = *(const bf16x8*)&As[wv * 16 + l15][quad * 8];
    #pragma unroll
    for (int ct = 0; ct < 8; ct++) {
      bf16x8 bF = *(const bf16x8*)&Ws[ct * 16 + l15][quad * 8];
      acc[ct] = __builtin_amdgcn_mfma_f32_16x16x32_bf16(aF, bF, acc[ct], 0, 0, 0);
    }
  }

  #pragma unroll
  for (int ct = 0; ct < 8; ct++) {
    int col = colBase + ct * 16 + l15;
    #pragma unroll
    for (int i = 0; i < 4; i++) {
      int row = rowBase + wv * 16 + quad * 4 + i;
      if (row >= Mrows) continue;
      float v = acc[ct][i];
      if (mode == 0) {
        v += bias[col];
        v = fmaxf(v, 0.f);
        int b = row / N0, n = row % N0;
        fout[((size_t)b * NTOK + 1 + n) * EMBED + col] = v;
      } else if (mode == 1) {
        int b = row / NPAD, n = row % NPAD;
        int sec = col / EMBED;
        int hh = (col % EMBED) / DH;
        int d = col & 63;
        u16* dst = (sec == 0) ? uo0 : ((sec == 1) ? uo1 : uo2);
        if (sec == 0) v *= QSCALE;
        dst[(((size_t)b * HEADS + hh) * NPAD + n) * DH + d] = f2bf(v);
      } else if (mode == 2) {
        v += bias[col];
        fout[(size_t)row * EMBED + col] += v;
      } else {
        v += bias[col];
        float full = fout[(size_t)row * EMBED + col] + v;
        fout[(size_t)row * EMBED + col] = full;
        int b = row / NTOK, t = row % NTOK;
        if (t > 0) fout2[((size_t)b * N0 + (t - 1)) * EMBED + col] = full;
      }
    }
  }
}

// ---- pinv generic GEMM: C = gamma*(A@B) + beta*A + eps*E  (bf16 dual out) --
// A,E: [batch][256][256] row-major. Bc: [batch][Nsize][256] = B^T row-major.
__global__ __launch_bounds__(256) void pinv_gemm(
    const u16* __restrict__ A, const u16* __restrict__ Bc,
    const u16* __restrict__ E,
    u16* __restrict__ Cr, u16* __restrict__ Cc,
    int Nsize, float gamma, float beta, float eps)
{
  __shared__ u16 As[64][40];
  __shared__ u16 Bs[64][40];
  int batch = blockIdx.z;
  const u16* Ab = A + (size_t)batch * MM * MM;
  const u16* Bb = Bc + (size_t)batch * MM * Nsize;
  int tid = threadIdx.x;
  int lane = tid & 63, wv = tid >> 6, quad = lane >> 4, l15 = lane & 15;
  int rowBase = blockIdx.y * 64, colBase = blockIdx.x * 64;
  int sr = tid >> 2, skc = (tid & 3) * 8;
  fp32x4 acc[4] = {fp32x4{0,0,0,0}, fp32x4{0,0,0,0}, fp32x4{0,0,0,0}, fp32x4{0,0,0,0}};

  for (int kb = 0; kb < MM; kb += 32) {
    __syncthreads();
    *(bf16x8*)&As[sr][skc] = *(const bf16x8*)&Ab[(size_t)(rowBase + sr) * MM + kb + skc];
    *(bf16x8*)&Bs[sr][skc] = *(const bf16x8*)&Bb[(size_t)(colBase + sr) * MM + kb + skc];
    __syncthreads();
    bf16x8 aF = *(const bf16x8*)&As[wv * 16 + l15][quad * 8];
    #pragma unroll
    for (int ct = 0; ct < 4; ct++) {
      bf16x8 bF = *(const bf16x8*)&Bs[ct * 16 + l15][quad * 8];
      acc[ct] = __builtin_amdgcn_mfma_f32_16x16x32_bf16(aF, bF, acc[ct], 0, 0, 0);
    }
  }

  #pragma unroll
  for (int ct = 0; ct < 4; ct++) {
    int col = colBase + ct * 16 + l15;
    #pragma unroll
    for (int i = 0; i < 4; i++) {
      int row = rowBase + wv * 16 + quad * 4 + i;
      float v = gamma * acc[ct][i];
      if (beta != 0.f) v += beta * bf2f(Ab[(size_t)row * MM + col]);
      if (eps != 0.f)  v += eps * bf2f(E[(size_t)batch * MM * MM + (size_t)row * MM + col]);
      u16 o = f2bf(v);
      if (Cr) Cr[(size_t)batch * MM * Nsize + (size_t)row * Nsize + col] = o;
      if (Cc) Cc[(size_t)batch * MM * Nsize + (size_t)col * MM + row] = o;
    }
  }
}

// ---- pinv fused dispatch: which=0: U = 7Y - Y@Y -> UC (col-major)
//                           which=1: M = z@Y      -> MR (row-major)
__global__ __launch_bounds__(256) void pinv_um(
    const u16* __restrict__ YR, const u16* __restrict__ YC,
    const u16* __restrict__ zR, u16* __restrict__ UC, u16* __restrict__ MR)
{
  __shared__ u16 As[64][40];
  __shared__ u16 Bs[64][40];
  int which = blockIdx.z >> 5;
  int batch = blockIdx.z & 31;
  const u16* Ab = (which ? zR : YR) + (size_t)batch * MM * MM;
  const u16* Bb = YC + (size_t)batch * MM * MM;
  int tid = threadIdx.x;
  int lane = tid & 63, wv = tid >> 6, quad = lane >> 4, l15 = lane & 15;
  int rowBase = blockIdx.y * 64, colBase = blockIdx.x * 64;
  int sr = tid >> 2, skc = (tid & 3) * 8;
  fp32x4 acc[4] = {fp32x4{0,0,0,0}, fp32x4{0,0,0,0}, fp32x4{0,0,0,0}, fp32x4{0,0,0,0}};

  for (int kb = 0; kb < MM; kb += 32) {
    __syncthreads();
    *(bf16x8*)&As[sr][skc] = *(const bf16x8*)&Ab[(size_t)(rowBase + sr) * MM + kb + skc];
    *(bf16x8*)&Bs[sr][skc] = *(const bf16x8*)&Bb[(size_t)(colBase + sr) * MM + kb + skc];
    __syncthreads();
    bf16x8 aF = *(const bf16x8*)&As[wv * 16 + l15][quad * 8];
    #pragma unroll
    for (int ct = 0; ct < 4; ct++) {
      bf16x8 bF = *(const bf16x8*)&Bs[ct * 16 + l15][quad * 8];
      acc[ct] = __builtin_amdgcn_mfma_f32_16x16x32_bf16(aF, bF, acc[ct], 0, 0, 0);
    }
  }

  #pragma unroll
  for (int ct = 0; ct < 4; ct++) {
    int col = colBase + ct * 16 + l15;
    #pragma unroll
    for (int i = 0; i < 4; i++) {
      int row = rowBase + wv * 16 + quad * 4 + i;
      if (which == 0) {
        float v = 7.f * bf2f(Ab[(size_t)row * MM + col]) - acc[ct][i];
        UC[(size_t)batch * MM * MM + (size_t)col * MM + row] = f2bf(v);
      } else {
        MR[(size_t)batch * MM * MM + (size_t)row * MM + col] = f2bf(acc[ct][i]);
      }
    }
  }
}

// ---------------- small utility kernels ----------------
__global__ void cls_kernel(const float* __restrict__ cls, float* __restrict__ h) {
  int t = blockIdx.x * blockDim.x + threadIdx.x;
  if (t >= BATCH * EMBED) return;
  int b = t / EMBED, c = t % EMBED;
  h[(size_t)b * NTOK * EMBED + c] = cls[c];
}

__global__ void zero_pad_kernel(u16* __restrict__ xpad) {
  int t = blockIdx.x * blockDim.x + threadIdx.x;
  const int per = 255 * EMBED;
  if (t >= BATCH * per) return;
  int b = t / per, r = t % per;
  xpad[(size_t)b * NPAD * EMBED + r] = 0;
}

__global__ __launch_bounds__(256) void ln_pad_kernel(
    const float* __restrict__ h, const float* __restrict__ g,
    const float* __restrict__ be, u16* __restrict__ xpad)
{
  __shared__ float red[4];
  int row = blockIdx.x;
  int b = row / NTOK, j = row % NTOK;
  const float* x = h + (size_t)row * EMBED;
  int tid = threadIdx.x;
  float v0 = x[tid], v1 = x[tid + 256];
  float mu = block_sum(v0 + v1, red) * (1.f / 512.f);
  float d0 = v0 - mu, d1 = v1 - mu;
  float var = block_sum(d0 * d0 + d1 * d1, red) * (1.f / 512.f);
  float inv = 1.f / sqrtf(var + 1e-5f);
  u16* o = xpad + ((size_t)b * NPAD + 255 + j) * EMBED;
  o[tid]       = f2bf(d0 * inv * g[tid]       + be[tid]);
  o[tid + 256] = f2bf(d1 * inv * g[tid + 256] + be[tid + 256]);
}

__global__ __launch_bounds__(256) void landmarks_kernel(
    const u16* __restrict__ q, const u16* __restrict__ k,
    float* __restrict__ qland, float* __restrict__ kland, u16* __restrict__ klandB)
{
  int bh = blockIdx.y;
  int m = blockIdx.x * 4 + (threadIdx.x >> 6);
  int d = threadIdx.x & 63;
  const u16* qb = q + (size_t)bh * NPAD * DH;
  const u16* kb = k + (size_t)bh * NPAD * DH;
  float sq = 0.f, sk = 0.f;
  int base = m * LSEG;
  #pragma unroll
  for (int t = 0; t < LSEG; t++) {
    sq += bf2f(qb[(size_t)(base + t) * DH + d]);
    sk += bf2f(kb[(size_t)(base + t) * DH + d]);
  }
  float kv = sk * (1.f / LSEG);
  qland[((size_t)bh * MM + m) * DH + d] = sq * (1.f / LSEG);
  kland[((size_t)bh * MM + m) * DH + d] = kv;
  klandB[((size_t)bh * MM + m) * DH + d] = f2bf(kv);
}

__global__ __launch_bounds__(256) void s2_softmax_kernel(
    const float* __restrict__ qland, const float* __restrict__ kland,
    u16* __restrict__ a2)
{
  __shared__ float qrow[64];
  __shared__ float red[4];
  int bh = blockIdx.y, m = blockIdx.x, tid = threadIdx.x;
  if (tid < 64) qrow[tid] = qland[((size_t)bh * MM + m) * DH + tid];
  __syncthreads();
  const float* kb = kland + (size_t)bh * MM * DH + (size_t)tid * DH;
  float s = 0.f;
  #pragma unroll 16
  for (int d = 0; d < 64; d++) s += qrow[d] * kb[d];
  float mx = block_max(s, red);
  float e = __expf(s - mx);
  float tot = block_sum(e, red);
  a2[((size_t)bh * MM + m) * MM + tid] = f2bf(e / tot);
}

__global__ void init_denom_kernel(float* __restrict__ denoms) {
  if (threadIdx.x < 2) denoms[threadIdx.x] = 0.f;
}

__global__ __launch_bounds__(256) void denom_kernel(
    const u16* __restrict__ a2, float* __restrict__ denoms)
{
  __shared__ float red[4];
  int bh = blockIdx.x, tid = threadIdx.x;
  const u16* A = a2 + (size_t)bh * MM * MM;
  float rs = 0.f, cs = 0.f;
  for (int j = 0; j < MM; j++) rs += bf2f(A[(size_t)tid * MM + j]);
  for (int i = 0; i < MM; i++) cs += bf2f(A[(size_t)i * MM + tid]);
  float mr = block_max(rs, red);
  float mc = block_max(cs, red);
  if (tid == 0) {
    atomicMax((int*)&denoms[0], __float_as_int(mr));
    atomicMax((int*)&denoms[1], __float_as_int(mc));
  }
}

// z0: zr = a2^T/denom (row-major), zc = a2/denom (= z^T row-major)
__global__ __launch_bounds__(256) void z0_trans_kernel(
    const u16* __restrict__ a2, const float* __restrict__ denoms,
    u16* __restrict__ zr, u16* __restrict__ zc)
{
  __shared__ u16 tile[64][72];
  int bh = blockIdx.z, i0 = blockIdx.y * 64, j0 = blockIdx.x * 64;
  int tid = threadIdx.x;
  float inv = 1.f / (denoms[0] * denoms[1]);
  const u16* Ab = a2 + (size_t)bh * MM * MM;
  #pragma unroll
  for (int it = 0; it < 4; it++) {
    int idx = it * 1024 + tid * 4;
    int r = idx >> 6, c = idx & 63;
    bf16x4 v = *(const bf16x4*)&Ab[(size_t)(i0 + r) * MM + j0 + c];
    u16 o[4];
    #pragma unroll
    for (int j = 0; j < 4; j++) o[j] = f2bf(bf2f((unsigned short)v[j]) * inv);
    *(bf16x4*)&zc[(size_t)bh * MM * MM + (size_t)(i0 + r) * MM + j0 + c] = *(bf16x4*)o;
    #pragma unroll
    for (int j = 0; j < 4; j++) tile[c + j][r] = o[j];
  }
  __syncthreads();
  #pragma unroll
  for (int it = 0; it < 4; it++) {
    int idx = it * 1024 + tid * 4;
    int r = idx >> 6, c = idx & 63;
    u16 o[4] = {tile[r][c], tile[r][c + 1], tile[r][c + 2], tile[r][c + 3]};
    *(bf16x4*)&zr[(size_t)bh * MM * MM + (size_t)(j0 + r) * MM + i0 + c] = *(bf16x4*)o;
  }
}

// ---- MFMA a3@v partial flash: block = 64 landmarks x 256-key segment --------
__global__ __launch_bounds__(256) void a3v_part_mfma(
    const float* __restrict__ qland, const u16* __restrict__ k,
    const u16* __restrict__ v, u16* __restrict__ Opart,
    float* __restrict__ mpart, float* __restrict__ lpart)
{
  __shared__ __align__(16) u16 qs[64][40];
  __shared__ __align__(16) u16 ks[256][72];   // reused for P[64][264]
  __shared__ __align__(16) u16 vt[64][72];
  int tid = threadIdx.x;
  int lane = tid & 63, wv = tid >> 6, quad = lane >> 4, l15 = lane & 15;
  int bh = blockIdx.y;
  int ltile = blockIdx.x & 3;
  int seg = blockIdx.x >> 2;
  int l0 = ltile * 64;
  int key0 = seg * 256;
  const float* qb = qland + (size_t)bh * MM * DH;
  const u16* kb = k + (size_t)bh * NPAD * DH;
  const u16* vb = v + (size_t)bh * NPAD * DH;

  {
    int sr = tid >> 2, dc = (tid & 3) * 16;
    const float4* p = (const float4*)&qb[(size_t)(l0 + sr) * DH + dc];
    float4 v0 = p[0], v1 = p[1], v2 = p[2], v3 = p[3];
    float va[16] = {v0.x,v0.y,v0.z,v0.w, v1.x,v1.y,v1.z,v1.w,
                    v2.x,v2.y,v2.z,v2.w, v3.x,v3.y,v3.z,v3.w};
    bf16x8 p0, p1;
    #pragma unroll
    for (int j = 0; j < 8; j++) { p0[j] = (short)f2bf(va[j]); p1[j] = (short)f2bf(va[8 + j]); }
    *(bf16x8*)&qs[sr][dc] = p0;
    *(bf16x8*)&qs[sr][dc + 8] = p1;
  }
  #pragma unroll
  for (int i = 0; i < 16; i++) {
    int idx = i * 1024 + tid * 4;
    int r = idx >> 6, c = idx & 63;
    *(bf16x4*)&ks[r][c] = *(const bf16x4*)&kb[(size_t)(key0 + r) * DH + c];
  }
  __syncthreads();

  fp32x4 sacc[16];
  #pragma unroll
  for (int ct = 0; ct < 16; ct++) sacc[ct] = fp32x4{0,0,0,0};
  bf16x8 aF0 = *(const bf16x8*)&qs[wv * 16 + l15][quad * 8];
  bf16x8 aF1 = *(const bf16x8*)&qs[wv * 16 + l15][32 + quad * 8];
  #pragma unroll
  for (int ct = 0; ct < 16; ct++) {
    bf16x8 b0 = *(const bf16x8*)&ks[ct * 16 + l15][quad * 8];
    bf16x8 b1 = *(const bf16x8*)&ks[ct * 16 + l15][32 + quad * 8];
    sacc[ct] = __builtin_amdgcn_mfma_f32_16x16x32_bf16(aF0, b0, sacc[ct], 0, 0, 0);
    sacc[ct] = __builtin_amdgcn_mfma_f32_16x16x32_bf16(aF1, b1, sacc[ct], 0, 0, 0);
  }

  float mrow[4], lrow[4];
  #pragma unroll
  for (int i = 0; i < 4; i++) {
    float m = -3.0e38f;
    #pragma unroll
    for (int ct = 0; ct < 16; ct++) m = fmaxf(m, sacc[ct][i]);
    #pragma unroll
    for (int o = 1; o < 16; o <<= 1) m = fmaxf(m, __shfl_xor(m, o));
    float s = 0.f;
    #pragma unroll
    for (int ct = 0; ct < 16; ct++) {
      float e = __expf(sacc[ct][i] - m);
      sacc[ct][i] = e;
      s += e;
    }
    #pragma unroll
    for (int o = 1; o < 16; o <<= 1) s += __shfl_xor(s, o);
    mrow[i] = m;
    lrow[i] = s;
  }
  __syncthreads();
  u16* P = &ks[0][0];
  #pragma unroll
  for (int ct = 0; ct < 16; ct++)
    #pragma unroll
    for (int i = 0; i < 4; i++)
      P[(size_t)(wv * 16 + quad * 4 + i) * 264 + ct * 16 + l15] = f2bf(sacc[ct][i]);
  __syncthreads();

  fp32x4 oacc[4] = {fp32x4{0,0,0,0}, fp32x4{0,0,0,0}, fp32x4{0,0,0,0}, fp32x4{0,0,0,0}};
  int dh = tid & 63, kgrp = tid >> 6;
  for (int ch = 0; ch < 4; ch++) {
    if (ch) __syncthreads();
    {
      int kbase = kgrp * 16;
      #pragma unroll
      for (int g = 0; g < 4; g++) {
        u16 pk[4];
        #pragma unroll
        for (int r = 0; r < 4; r++)
          pk[r] = vb[(size_t)(key0 + ch * 64 + kbase + g * 4 + r) * DH + dh];
        *(bf16x4*)&vt[dh][kbase + g * 4] = *(bf16x4*)pk;
      }
    }
    __syncthreads();
    #pragma unroll
    for (int ks2 = 0; ks2 < 2; ks2++) {
      bf16x8 aP = *(const bf16x8*)&P[(size_t)(wv * 16 + l15) * 264 + ch * 64 + ks2 * 32 + quad * 8];
      #pragma unroll
      for (int ct = 0; ct < 4; ct++) {
        bf16x8 bV = *(const bf16x8*)&vt[ct * 16 + l15][ks2 * 32 + quad * 8];
        oacc[ct] = __builtin_amdgcn_mfma_f32_16x16x32_bf16(aP, bV, oacc[ct], 0, 0, 0);
      }
    }
  }

  size_t base = ((size_t)seg * BH + bh) * MM + l0;
  #pragma unroll
  for (int ct = 0; ct < 4; ct++)
    #pragma unroll
    for (int i = 0; i < 4; i++) {
      int row = wv * 16 + quad * 4 + i;
      Opart[(base + row) * DH + ct * 16 + l15] = f2bf(oacc[ct][i]);
    }
  if (l15 == 0) {
    #pragma unroll
    for (int i = 0; i < 4; i++) {
      int row = wv * 16 + quad * 4 + i;
      mpart[base + row] = mrow[i];
      lpart[base + row] = lrow[i];
    }
  }
}

// merge partials -> kv^T (col-major for the z@kv GEMM's B operand)
__global__ __launch_bounds__(256) void a3v_merge_kernel(
    const u16* __restrict__ Opart, const float* __restrict__ mpart,
    const float* __restrict__ lpart, u16* __restrict__ kvT)
{
  int bh = blockIdx.y;
  int lbase = blockIdx.x * 64;
  int d = threadIdx.x & 63, lsub = threadIdx.x >> 6;
  for (int li = lsub; li < 64; li += 4) {
    int lm = lbase + li;
    float M = -3.0e38f;
    #pragma unroll
    for (int s = 0; s < NSEG; s++)
      M = fmaxf(M, mpart[((size_t)s * BH + bh) * MM + lm]);
    float L = 0.f, O = 0.f;
    #pragma unroll
    for (int s = 0; s < NSEG; s++) {
      size_t idx = ((size_t)s * BH + bh) * MM + lm;
      float w = __expf(mpart[idx] - M);
      L += lpart[idx] * w;
      O += bf2f(Opart[idx * DH + d]) * w;
    }
    kvT[((size_t)bh * DH + d) * MM + lm] = f2bf(O / L);
  }
}

// Toeplitz conv weights: toepB[layer][head][r=0..63][t=0..95] = w[t-r] (banded)
__global__ void prep_toep_kernel(const float* __restrict__ resw0,
                                 const float* __restrict__ resw1,
                                 u16* __restrict__ toepB)
{
  int i = blockIdx.x * 256 + threadIdx.x;
  if (i >= 2 * 8 * 64 * 96) return;
  int t = i % 96, r = (i / 96) % 64, hh = (i / (96 * 64)) % 8, l = i / (96 * 64 * 8);
  const float* rw = l ? resw1 : resw0;
  int tap = t - r;
  float v = (tap >= 0 && tap <= 32) ? rw[hh * 33 + tap] : 0.f;
  toepB[i] = f2bf(v);
}

// ---- attn1: grouped global frags + Toeplitz-MFMA conv, 64 rows/block --------
// launch_bounds(256,2): high VGPR budget so load groups pipeline (R8 post-mortem:
// VGPR=56 serialized ~100 global loads at L2 latency -> 82us floor)
__global__ __launch_bounds__(256, 2) void attn1_mfma(
    const u16* __restrict__ q, const u16* __restrict__ klandB,
    const u16* __restrict__ kv2T, const u16* __restrict__ v,
    const u16* __restrict__ toep, u16* __restrict__ attn)
{
  __shared__ __align__(16) u16 buf[64 * 264];
  int tid = threadIdx.x;
  int lane = tid & 63, wv = tid >> 6, quad = lane >> 4, l15 = lane & 15;
  int bh = blockIdx.y, b = bh >> 3, hh = bh & 7;
  int n0 = 255 + blockIdx.x * 64;
  const u16* qb  = q + (size_t)bh * NPAD * DH;
  const u16* klb = klandB + (size_t)bh * MM * DH;
  const u16* kvb = kv2T + (size_t)bh * DH * MM;
  const u16* vb  = v + (size_t)bh * NPAD * DH;
  const u16* tb  = toep + (size_t)hh * 64 * 96;

  // S = Q @ kland^T, loads batched in 2 groups of 16
  int qrow = n0 + wv * 16 + l15; if (qrow > NPAD - 1) qrow = NPAD - 1;
  bf16x8 aF0 = *(const bf16x8*)&qb[(size_t)qrow * DH + quad * 8];
  bf16x8 aF1 = *(const bf16x8*)&qb[(size_t)qrow * DH + 32 + quad * 8];
  fp32x4 sacc[16];
  #pragma unroll
  for (int ct = 0; ct < 16; ct++) sacc[ct] = fp32x4{0,0,0,0};
  #pragma unroll
  for (int g = 0; g < 2; g++) {
    bf16x8 b0[8], b1[8];
    #pragma unroll
    for (int j = 0; j < 8; j++) {
      int ct = g * 8 + j;
      b0[j] = *(const bf16x8*)&klb[(size_t)(ct * 16 + l15) * DH + quad * 8];
      b1[j] = *(const bf16x8*)&klb[(size_t)(ct * 16 + l15) * DH + 32 + quad * 8];
    }
    #pragma unroll
    for (int j = 0; j < 8; j++) {
      int ct = g * 8 + j;
      sacc[ct] = __builtin_amdgcn_mfma_f32_16x16x32_bf16(aF0, b0[j], sacc[ct], 0, 0, 0);
      sacc[ct] = __builtin_amdgcn_mfma_f32_16x16x32_bf16(aF1, b1[j], sacc[ct], 0, 0, 0);
    }
  }
  // register softmax (row = quad*4+i, cols over ct x l15)
  #pragma unroll
  for (int i = 0; i < 4; i++) {
    float m = -3.0e38f;
    #pragma unroll
    for (int ct = 0; ct < 16; ct++) m = fmaxf(m, sacc[ct][i]);
    #pragma unroll
    for (int o = 1; o < 16; o <<= 1) m = fmaxf(m, __shfl_xor(m, o));
    float s = 0.f;
    #pragma unroll
    for (int ct = 0; ct < 16; ct++) {
      float e = __expf(sacc[ct][i] - m);
      sacc[ct][i] = e;
      s += e;
    }
    #pragma unroll
    for (int o = 1; o < 16; o <<= 1) s += __shfl_xor(s, o);
    float inv = 1.f / s;
    #pragma unroll
    for (int ct = 0; ct < 16; ct++) sacc[ct][i] *= inv;
  }
  // write P (normalized bf16), stride 264
  #pragma unroll
  for (int ct = 0; ct < 16; ct++)
    #pragma unroll
    for (int i = 0; i < 4; i++)
      buf[(size_t)(wv * 16 + quad * 4 + i) * 264 + ct * 16 + l15] = f2bf(sacc[ct][i]);
  __syncthreads();

  // O = P @ kv2, loads batched in 2 groups of (4 aP + 16 bV)
  fp32x4 oacc[4] = {fp32x4{0,0,0,0}, fp32x4{0,0,0,0}, fp32x4{0,0,0,0}, fp32x4{0,0,0,0}};
  #pragma unroll
  for (int g = 0; g < 2; g++) {
    bf16x8 ap[4], bv[4][4];
    #pragma unroll
    for (int j = 0; j < 4; j++) {
      int ks = g * 4 + j;
      ap[j] = *(const bf16x8*)&buf[(size_t)(wv * 16 + l15) * 264 + ks * 32 + quad * 8];
      #pragma unroll
      for (int ct = 0; ct < 4; ct++)
        bv[j][ct] = *(const bf16x8*)&kvb[(size_t)(ct * 16 + l15) * MM + ks * 32 + quad * 8];
    }
    #pragma unroll
    for (int j = 0; j < 4; j++)
      #pragma unroll
      for (int ct = 0; ct < 4; ct++)
        oacc[ct] = __builtin_amdgcn_mfma_f32_16x16x32_bf16(ap[j], bv[j][ct], oacc[ct], 0, 0, 0);
  }
  __syncthreads();   // P dead; reuse buf as vwinT[64][104]

  // stage v window transposed: vwinT[d][t], coalesced 128B row reads
  {
    int d = lane;
    #pragma unroll
    for (int tt4 = 0; tt4 < 6; tt4++) {
      u16 vals[4];
      #pragma unroll
      for (int j = 0; j < 4; j++) {
        int t = wv * 24 + tt4 * 4 + j;
        int g = n0 - 16 + t;
        vals[j] = (g <= NPAD - 1) ? vb[(size_t)g * DH + d] : (u16)0;
      }
      *(bf16x4*)&buf[d * 104 + wv * 24 + tt4 * 4] = *(bf16x4*)vals;
    }
  }
  __syncthreads();

  // conv: oacc += Toep(64x96) @ vwinT^T, toep frags preloaded
  {
    bf16x8 at[3];
    #pragma unroll
    for (int kc = 0; kc < 3; kc++)
      at[kc] = *(const bf16x8*)&tb[(size_t)(wv * 16 + l15) * 96 + kc * 32 + quad * 8];
    #pragma unroll
    for (int kc = 0; kc < 3; kc++) {
      #pragma unroll
      for (int ct = 0; ct < 4; ct++) {
        bf16x8 bW = *(const bf16x8*)&buf[(ct * 16 + l15) * 104 + kc * 32 + quad * 8];
        oacc[ct] = __builtin_amdgcn_mfma_f32_16x16x32_bf16(at[kc], bW, oacc[ct], 0, 0, 0);
      }
    }
  }

  #pragma unroll
  for (int ct = 0; ct < 4; ct++) {
    int c = ct * 16 + l15;
    #pragma unroll
    for (int i = 0; i < 4; i++) {
      int rl = wv * 16 + quad * 4 + i;
      int n = n0 + rl;
      if (n > NPAD - 1) continue;
      attn[((size_t)b * NTOK + (n - 255)) * EMBED + hh * DH + c] = f2bf(oacc[ct][i]);
    }
  }
}

// combine 7x7 + 5x5 + 3x3 + identity into one 7x7 depthwise kernel
__global__ void prep_wcomb_kernel(
    const float* __restrict__ pw7, const float* __restrict__ pw5,
    const float* __restrict__ pw3, const float* __restrict__ pb7,
    const float* __restrict__ pb5, const float* __restrict__ pb3,
    float* __restrict__ wcomb, float* __restrict__ biasc)
{
  int i = blockIdx.x * blockDim.x + threadIdx.x;
  if (i < EMBED * 49) {
    int c = i / 49, tap = i % 49;
    int ky = tap / 7, kx = tap % 7;
    float v = pw7[c * 49 + tap];
    if (ky >= 1 && ky <= 5 && kx >= 1 && kx <= 5) v += pw5[c * 25 + (ky - 1) * 5 + (kx - 1)];
    if (ky >= 2 && ky <= 4 && kx >= 2 && kx <= 4) v += pw3[c * 9 + (ky - 2) * 3 + (kx - 2)];
    if (ky == 3 && kx == 3) v += 1.f;
    wcomb[tap * EMBED + c] = v;
  }
  if (i < EMBED) biasc[i] = pb7[i] + pb5[i] + pb3[i];
}

// float4-per-thread depthwise conv: block (32,8) = 128 ch x 8 positions
__global__ __launch_bounds__(256) void dwconv_kernel(
    const float* __restrict__ tmp, const float* __restrict__ wcomb,
    const float* __restrict__ biasc, float* __restrict__ h)
{
  __shared__ float4 wsm[49][32];
  int tx = threadIdx.x;
  int ty = threadIdx.y;
  int cb = blockIdx.x * 128;
  int c = cb + tx * 4;
  int b = blockIdx.z;
  int n = blockIdx.y * 8 + ty;
  int y = n >> 6, x = n & 63;
  int tid = ty * 32 + tx;
  for (int i = tid; i < 49 * 32; i += 256) {
    int tap = i >> 5, g = i & 31;
    wsm[tap][g] = *(const float4*)&wcomb[tap * EMBED + cb + g * 4];
  }
  __syncthreads();
  const float* src = tmp + (size_t)b * N0 * EMBED;
  float4 acc = *(const float4*)&biasc[c];
  #pragma unroll
  for (int ky = 0; ky < 7; ky++) {
    int yy = y + ky - 3;
    if (yy < 0 || yy >= 64) continue;
    #pragma unroll
    for (int kx = 0; kx < 7; kx++) {
      int xx = x + kx - 3;
      if (xx < 0 || xx >= 64) continue;
      float4 vv = *(const float4*)&src[((size_t)yy * 64 + xx) * EMBED + c];
      float4 w = wsm[ky * 7 + kx][tx];
      acc.x += vv.x * w.x;
      acc.y += vv.y * w.y;
      acc.z += vv.z * w.z;
      acc.w += vv.w * w.w;
    }
  }
  *(float4*)&h[((size_t)b * NTOK + 1 + n) * EMBED + c] = acc;
}

__global__ __launch_bounds__(256) void final_kernel(
    const float* __restrict__ h, const float* __restrict__ g,
    const float* __restrict__ be, const float* __restrict__ W2,
    const float* __restrict__ b2, float* __restrict__ out)
{
  __shared__ float red[4];
  int b = blockIdx.x, tid = threadIdx.x;
  const float* x = h + (size_t)b * NTOK * EMBED;
  float v0 = x[tid], v1 = x[tid + 256];
  float mu = block_sum(v0 + v1, red) * (1.f / 512.f);
  float d0 = v0 - mu, d1 = v1 - mu;
  float var = block_sum(d0 * d0 + d1 * d1, red) * (1.f / 512.f);
  float inv = 1.f / sqrtf(var + 1e-5f);
  float xn0 = d0 * inv * g[tid] + be[tid];
  float xn1 = d1 * inv * g[tid + 256] + be[tid + 256];
  float l0 = block_sum(xn0 * W2[tid] + xn1 * W2[tid + 256], red);
  float l1 = block_sum(xn0 * W2[512 + tid] + xn1 * W2[512 + tid + 256], red);
  if (tid == 0) {
    l0 += b2[0]; l1 += b2[1];
    out[b * 2 + 0] = l0;
    out[b * 2 + 1] = l1;
    float mx = fmaxf(l0, l1);
    float e0 = expf(l0 - mx), e1 = expf(l1 - mx);
    float s = e0 + e1;
    out[8 + b * 2 + 0] = e0 / s;
    out[8 + b * 2 + 1] = e1 / s;
    out[16 + b] = (l1 > l0) ? 1.f : 0.f;
  }
}

// ------------------------------- host side -----------------------------------
extern "C" void kernel_launch(void* const* d_in, const int* in_sizes, int n_in,
                              void* d_out, int out_size, void* d_ws, size_t ws_size,
                              hipStream_t stream)
{
  const float* data = (const float*)d_in[0];
  const float* W1   = (const float*)d_in[1];
  const float* b1   = (const float*)d_in[2];
  const float* cls  = (const float*)d_in[3];
  const float* lng[2]  = {(const float*)d_in[4],  (const float*)d_in[10]};
  const float* lnb[2]  = {(const float*)d_in[5],  (const float*)d_in[11]};
  const float* Wqkv[2] = {(const float*)d_in[6],  (const float*)d_in[12]};
  const float* Wo[2]   = {(const float*)d_in[7],  (const float*)d_in[13]};
  const float* bo[2]   = {(const float*)d_in[8],  (const float*)d_in[14]};
  const float* resw[2] = {(const float*)d_in[9],  (const float*)d_in[15]};
  const float* pw7 = (const float*)d_in[16];
  const float* pb7 = (const float*)d_in[17];
  const float* pw5 = (const float*)d_in[18];
  const float* pb5 = (const float*)d_in[19];
  const float* pw3 = (const float*)d_in[20];
  const float* pb3 = (const float*)d_in[21];
  const float* lnfg = (const float*)d_in[22];
  const float* lnfb = (const float*)d_in[23];
  const float* W2  = (const float*)d_in[24];
  const float* b2  = (const float*)d_in[25];

  float* ws = (float*)d_ws;
  size_t off = 0;
  auto alloc = [&](size_t n) { float* p = ws + off; off += n; return p; };
  float* hbuf   = alloc((size_t)BATCH * NTOK * EMBED);          // fp32
  float* xpadf  = alloc((size_t)BATCH * NPAD * EMBED);          // bf16 (half) + attn reuse
  float* qbuff  = alloc((size_t)BH * NPAD * DH);                // q bf16 / databf / conv tmp fp32
  float* kbuff  = alloc((size_t)BH * NPAD * DH);                // k bf16 (half)
  float* vbuff  = alloc((size_t)BH * NPAD * DH);                // v bf16 (half) + W1bf tail
  float* qland  = alloc((size_t)BH * MM * DH);
  float* kland  = alloc((size_t)BH * MM * DH);
  float* klandBf= alloc((size_t)BH * MM * DH / 2);              // bf16
  float* a2f    = alloc((size_t)BH * MM * MM / 2);              // bf16
  float* zaRf   = alloc((size_t)BH * MM * MM / 2);
  float* zaCf   = alloc((size_t)BH * MM * MM / 2);
  float* zbRf   = alloc((size_t)BH * MM * MM / 2);
  float* zbCf   = alloc((size_t)BH * MM * MM / 2);
  float* YRf    = alloc((size_t)BH * MM * MM / 2);
  float* YCf    = alloc((size_t)BH * MM * MM / 2);
  float* UCf    = alloc((size_t)BH * MM * MM / 2);
  float* MRf    = alloc((size_t)BH * MM * MM / 2);
  float* kvTf   = alloc((size_t)BH * MM * DH / 2);
  float* kv2Tf  = alloc((size_t)BH * MM * DH / 2);
  float* wqkvbf = alloc((size_t)2 * 3 * EMBED * EMBED / 2);     // bf16 x2 layers
  float* wobf   = alloc((size_t)2 * EMBED * EMBED / 2);
  float* toepf  = alloc((size_t)2 * 8 * 64 * 96 / 2);           // bf16 toeplitz x2 layers
  float* wcomb  = alloc(49 * EMBED);
  float* biasc  = alloc(EMBED);
  float* denoms = alloc(64);
  float* mpart  = alloc((size_t)NSEG * BH * MM);
  float* lpart  = alloc((size_t)NSEG * BH * MM);

  u16* xpadB = (u16*)xpadf;
  u16* qB = (u16*)qbuff;
  u16* kB = (u16*)kbuff;
  u16* vB = (u16*)vbuff;
  u16* klandB = (u16*)klandBf;
  u16* a2B = (u16*)a2f;
  u16* zaR = (u16*)zaRf; u16* zaC = (u16*)zaCf;
  u16* zbR = (u16*)zbRf; u16* zbC = (u16*)zbCf;
  u16* YR = (u16*)YRf; u16* YC = (u16*)YCf;
  u16* UC = (u16*)UCf; u16* MR = (u16*)MRf;
  u16* kvT = (u16*)kvTf; u16* kv2T = (u16*)kv2Tf;
  u16* attnB = xpadB;
  u16* OpartB = zaR;                       // overlay: free until z0_trans
  u16* databf = (u16*)qbuff;               // overlay: consumed by input GEMM only
  u16* W1bf = (u16*)vbuff;                 // overlay: consumed by input GEMM only
  u16* WqkvB[2] = {(u16*)wqkvbf, (u16*)wqkvbf + (size_t)3 * EMBED * EMBED};
  u16* WoB[2]   = {(u16*)wobf,   (u16*)wobf + (size_t)EMBED * EMBED};
  u16* toepB[2] = {(u16*)toepf,  (u16*)toepf + (size_t)8 * 64 * 96};
  float* convtmp = qbuff;

  // ---- one-time bf16 conversions / prep ----
  int ndata = BATCH * N0 * CIN;
  f2bf_kernel<<<dim3((ndata / 8 + 255) / 256), 256, 0, stream>>>(data, databf, ndata);
  f2bf_kernel<<<dim3((EMBED * CIN / 8 + 255) / 256), 256, 0, stream>>>(W1, W1bf, EMBED * CIN);
  for (int l = 0; l < 2; l++) {
    f2bf_kernel<<<dim3((3 * EMBED * EMBED / 8 + 255) / 256), 256, 0, stream>>>(Wqkv[l], WqkvB[l], 3 * EMBED * EMBED);
    f2bf_kernel<<<dim3((EMBED * EMBED / 8 + 255) / 256), 256, 0, stream>>>(Wo[l], WoB[l], EMBED * EMBED);
  }
  prep_toep_kernel<<<dim3((2 * 8 * 64 * 96 + 255) / 256), 256, 0, stream>>>(
      resw[0], resw[1], (u16*)toepf);

  gemm_abt<<<dim3(EMBED / 128, (BATCH * N0) / 64), 256, 0, stream>>>(
      databf, W1bf, BATCH * N0, EMBED, CIN, b1, hbuf, nullptr, nullptr, nullptr, nullptr, 0);
  cls_kernel<<<dim3((BATCH * EMBED + 255) / 256), 256, 0, stream>>>(cls, hbuf);

  for (int layer = 0; layer < 2; layer++) {
    ln_pad_kernel<<<dim3(BATCH * NTOK), 256, 0, stream>>>(hbuf, lng[layer], lnb[layer], xpadB);
    zero_pad_kernel<<<dim3((BATCH * 255 * EMBED + 255) / 256), 256, 0, stream>>>(xpadB);
    gemm_abt<<<dim3((3 * EMBED) / 128, (BATCH * NPAD) / 64), 256, 0, stream>>>(
        xpadB, WqkvB[layer], BATCH * NPAD, 3 * EMBED, EMBED, nullptr,
        nullptr, nullptr, qB, kB, vB, 1);
    landmarks_kernel<<<dim3(MM / 4, BH), 256, 0, stream>>>(qB, kB, qland, kland, klandB);
    s2_softmax_kernel<<<dim3(MM, BH), 256, 0, stream>>>(qland, kland, a2B);
    init_denom_kernel<<<1, 64, 0, stream>>>(denoms);
    denom_kernel<<<dim3(BH), 256, 0, stream>>>(a2B, denoms);

    // a3@v before pinv so Opart can overlay the pinv scratch
    a3v_part_mfma<<<dim3(4 * NSEG, BH), 256, 0, stream>>>(
        qland, kB, vB, OpartB, mpart, lpart);
    a3v_merge_kernel<<<dim3(MM / 64, BH), 256, 0, stream>>>(OpartB, mpart, lpart, kvT);

    z0_trans_kernel<<<dim3(4, 4, BH), 256, 0, stream>>>(a2B, denoms, zaR, zaC);
    u16 *zinR = zaR, *zinC = zaC, *zoutR = zbR, *zoutC = zbC;
    for (int it = 0; it < 6; it++) {
      // Y = a2 @ z
      pinv_gemm<<<dim3(4, 4, BH), 256, 0, stream>>>(
          a2B, zinC, nullptr, YR, YC, MM, 1.f, 0.f, 0.f);
      // U = 7Y - Y@Y ; M = z@Y   (fused, independent products)
      pinv_um<<<dim3(4, 4, 2 * BH), 256, 0, stream>>>(YR, YC, zinR, UC, MR);
      // z' = 0.25*(M@U) - 3.75*M + 3.25*z
      pinv_gemm<<<dim3(4, 4, BH), 256, 0, stream>>>(
          MR, UC, zinR, zoutR, zoutC, MM, 0.25f, -3.75f, 3.25f);
      u16* t;
      t = zinR; zinR = zoutR; zoutR = t;
      t = zinC; zinC = zoutC; zoutC = t;
    }
    // kv2T[dh][m] = (z @ kv)^T
    pinv_gemm<<<dim3(1, 4, BH), 256, 0, stream>>>(
        zinR, kvT, nullptr, nullptr, kv2T, DH, 1.f, 0.f, 0.f);
    attn1_mfma<<<dim3((NTOK + 63) / 64, BH), 256, 0, stream>>>(
        qB, klandB, kv2T, vB, toepB[layer], attnB);
    gemm_abt<<<dim3(EMBED / 128, (BATCH * NTOK + 63) / 64), 256, 0, stream>>>(
        attnB, WoB[layer], BATCH * NTOK, EMBED, EMBED, bo[layer], hbuf,
        (layer == 0) ? convtmp : nullptr, nullptr, nullptr, nullptr,
        (layer == 0) ? 3 : 2);

    if (layer == 0) {
      prep_wcomb_kernel<<<dim3((EMBED * 49 + 255) / 256), 256, 0, stream>>>(
          pw7, pw5, pw3, pb7, pb5, pb3, wcomb, biasc);
      dwconv_kernel<<<dim3(EMBED / 128, N0 / 8, BATCH), dim3(32, 8), 0, stream>>>(
          convtmp, wcomb, biasc, hbuf);
    }
  }

  final_kernel<<<dim3(BATCH), 256, 0, stream>>>(hbuf, lnfg, lnfb, W2, b2, (float*)d_out);
}